// Round 1
// 69.170 us; speedup vs baseline: 1.0058x; 1.0058x over previous
//
#include <hip/hip_runtime.h>
#include <math.h>

// N=16384 atoms, 64 graphs (~256 atoms each), K=32, r=5.
#define KNBR 32
#define STOP2 25.0
#define BAND 1.0e-3f    // fp32 filter guard band (fp32 d2 error <= ~2e-5)
#define CAP 64          // per-atom in-band candidates (Poisson mean ~5)
#define WPB 4           // waves per block (waves are fully independent)
#define APW 2           // atoms per wave
#define APB (WPB*APW)   // 8 atoms per block

// R8 vs R7: pos (196 KB) and batch (64 KB) are fully L2-resident and each
// wave's candidate window (~6 KB) is L1-resident, so the LDS staging +
// __syncthreads of R7 was pure overhead (guide Common-mistake #7): every
// wave stalled at a block-wide barrier behind the slowest staging load.
// R8 reads candidates straight from global (L1/L2 hits, shared by the 4
// waves of a block), makes every wave fully independent (no barrier, no
// block-wide LDS), and fuses the two per-atom epilogues into one full-wave
// pass (lanes 0-31 -> atom 0, lanes 32-63 -> atom 1; the two atoms' output
// rows are adjacent, giving contiguous 256B stores per instruction).
// Grid 2048 blocks x 4 waves = 8192 waves = 32 waves/CU in one round
// (__launch_bounds__(256,8) pins VGPR<=64 for full residency).
// Selection math (fp32 band + fp64 refine, (d2,j) rank, lower-index ties ==
// jax.lax.top_k order) is bit-identical to R1-R7.
__global__ __launch_bounds__(WPB * 64, 8)
void radius_graph_knn(const float* __restrict__ pos,
                      const int* __restrict__ batch,
                      float* __restrict__ out, int n) {
    __shared__ int jbuf[WPB][APW][CAP];   // per-wave scratch, no barriers
    __shared__ int win[WPB][APW][KNBR];

    const int tid  = threadIdx.x;
    const int lane = tid & 63;
    const int w    = tid >> 6;
    const int i0w  = (blockIdx.x * WPB + w) * APW;   // first atom of wave

    // ---- this wave's APW atoms (broadcast loads, L2-resident)
    int ia[APW]; int ba[APW];
    float xa[APW], ya[APW], za[APW];
    #pragma unroll
    for (int a = 0; a < APW; ++a) {
        const int i = min(i0w + a, n - 1);
        ia[a] = i;
        xa[a] = pos[3 * i]; ya[a] = pos[3 * i + 1]; za[a] = pos[3 * i + 2];
        ba[a] = batch[i];
    }
    const int bFirst = ba[0];
    const int bLast  = ba[APW - 1];

    // ---- candidate chunk-range detect (one gather round + one ballot).
    // Chunk cw intersects graphs [bFirst,bLast] iff batch[64cw] <= bLast
    // && batch[64cw+63] >= bFirst. batch sorted -> relevant chunks are a
    // contiguous run containing c0 (graphs ~256 atoms; +-32 chunks = +-2048
    // atoms covers any union, >100 sigma margin).
    const int nchunks = (n + 63) >> 6;
    const int c0 = i0w >> 6;
    const int cw = c0 - 32 + lane;
    bool rel = false;
    if (cw >= 0 && cw < nchunks) {
        const int s = batch[cw << 6];
        const int e = batch[min(n - 1, (cw << 6) + 63)];
        rel = (s <= bLast) && (e >= bFirst);
    }
    const unsigned long long cm = __ballot(rel);
    const int cLo = c0 - 32 + (int)__builtin_ctzll(cm);
    const int cHi = c0 - 32 + (63 - (int)__builtin_clzll(cm));
    const int base = cLo << 6;
    const int stagedN = min(n, (cHi + 1) << 6) - base;   // multiple of 64

    // ---- fused dual-atom fp32 band scan straight from global (L1-hit after
    // first touch; 4 waves/block share the same ~6KB window). One load per
    // candidate serves both atoms; compact survivors per atom (ballot+prefix).
    int cnt[APW] = {0, 0};
    for (int t0 = 0; t0 < stagedN; t0 += 64) {
        const int t = t0 + lane;
        const int tc = min(t, stagedN - 1);
        const int j = base + tc;
        const float xj = pos[3 * j], yj = pos[3 * j + 1], zj = pos[3 * j + 2];
        const int bj = batch[j];
        #pragma unroll
        for (int a = 0; a < APW; ++a) {
            const float dx = xa[a] - xj, dy = ya[a] - yj, dz = za[a] - zj;
            const float d2 = dx * dx + dy * dy + dz * dz;
            const bool valid = (t < stagedN) & (j != ia[a]) & (bj == ba[a]) &
                               (d2 <= 25.0f + BAND);
            const unsigned long long m = __ballot(valid);
            const int p = cnt[a] + __popcll(m & ((1ULL << lane) - 1ULL));
            if (valid && p < CAP) jbuf[w][a][p] = j;
            cnt[a] += __popcll(m);
        }
    }

    // ---- per atom: fp64 refine + (d2,j) rank. Per-wave LDS ops are
    // program-ordered, so no barrier needed anywhere.
    int nsel[APW];
    #pragma unroll
    for (int a = 0; a < APW; ++a) {
        const int count = min(cnt[a], CAP);
        double d2e = 1e300;
        int jmine = 0x7fffffff;
        bool valid = false;
        if (lane < count) {
            const int j = jbuf[w][a][lane];
            const double dx = (double)xa[a] - (double)pos[3 * j];
            const double dy = (double)ya[a] - (double)pos[3 * j + 1];
            const double dz = (double)za[a] - (double)pos[3 * j + 2];
            d2e = dx * dx + dy * dy + dz * dz;
            jmine = j;
            valid = (d2e <= STOP2);           // exact cutoff, as R1-R7
        }
        const unsigned long long vm = __ballot(valid);
        int ns = __popcll(vm);
        if (ns > KNBR) ns = KNBR;
        nsel[a] = ns;
        int rank = 0;
        for (int s = 0; s < count; ++s) {
            const double ds = __shfl(d2e, s);
            const int    js = __shfl(jmine, s);
            const bool   vs = (vm >> s) & 1ULL;
            rank += (vs && (ds < d2e || (ds == d2e && js < jmine))) ? 1 : 0;
        }
        if (valid && rank < KNBR) win[w][a][rank] = jmine;
    }

    // ---- fused full-wave epilogue: lanes 0-31 -> atom 0, 32-63 -> atom 1.
    // Atom rows are adjacent (i*K, (i+1)*K) -> each store instruction covers
    // 2x128B contiguous.
    const long long NK = (long long)n * KNBR;
    float* row0 = out;
    float* row1 = out + NK;
    float* wgt  = out + 2 * NK;
    float* vec  = out + 3 * NK;
    float* msk  = out + 6 * NK;

    const int a = lane >> 5;          // which atom this lane serves
    const int s = lane & 31;          // neighbor slot
    const int   i  = a ? ia[1] : ia[0];
    const float xi = a ? xa[1] : xa[0];
    const float yi = a ? ya[1] : ya[0];
    const float zi = a ? za[1] : za[0];
    const int   ns = a ? nsel[1] : nsel[0];
    const bool v = s < ns;
    const int j = v ? win[w][a][s] : i;           // pad with self (vec = 0)
    const float vx = xi - pos[3 * j];
    const float vy = yi - pos[3 * j + 1];
    const float vz = zi - pos[3 * j + 2];
    const float ww = v ? sqrtf(vx * vx + vy * vy + vz * vz) : 0.0f;
    const long long o = (long long)i * KNBR + s;
    row0[o] = (float)i;
    row1[o] = (float)j;
    wgt[o]  = ww;
    vec[3 * o + 0] = v ? vx : 0.0f;
    vec[3 * o + 1] = v ? vy : 0.0f;
    vec[3 * o + 2] = v ? vz : 0.0f;
    msk[o]  = v ? 1.0f : 0.0f;
}

extern "C" void kernel_launch(void* const* d_in, const int* in_sizes, int n_in,
                              void* d_out, int out_size, void* d_ws, size_t ws_size,
                              hipStream_t stream) {
    const float* pos   = (const float*)d_in[0];
    const int*   batch = (const int*)d_in[1];
    float* out = (float*)d_out;
    int n = in_sizes[1];  // 16384 atoms

    const int block = WPB * 64;
    const int grid = (n + APB - 1) / APB;  // 2048 blocks, 2 atoms per wave
    radius_graph_knn<<<grid, block, 0, stream>>>(pos, batch, out, n);
}

// Round 2
// 68.728 us; speedup vs baseline: 1.0122x; 1.0064x over previous
//
#include <hip/hip_runtime.h>
#include <math.h>

// N=16384 atoms, 64 graphs (~256 atoms each), K=32, r=5.
#define KNBR 32
#define STOP2 25.0
#define BAND 1.0e-3f    // fp32 filter guard band (fp32 d2 error <= ~2e-5)
#define CAP 64          // per-atom in-band candidates (Poisson mean ~5)
#define WPB 4           // waves per block (waves are fully independent)
#define APW 2           // atoms per wave
#define APB (WPB*APW)   // 8 atoms per block

// R9 vs R8 (R8 was neutral vs R7 -> staging/barrier was never the cost; the
// shared serial structure is). R9 attacks the per-wave latency chains:
//  (1) refine+rank fused across both atoms via half-waves: lanes 0-31 handle
//      atom 0's candidates, lanes 32-63 atom 1's. One fp64 gather round, one
//      ballot, one width-32 shuffle rank loop of length max(count0,count1)
//      instead of two sequential full passes. In-band count per atom is ~5-10
//      (P(>32) ~ 1e-20); a bit-identical serial fallback guards count>32.
//  (2) scan loop software-pipelined: next iteration's 4 loads issue before
//      the current iteration's ballot/prefix chains, overlapping L1/L2
//      latency with the serial ballot arithmetic.
// Selection math (fp32 band + fp64 refine, (d2,j) rank, lower-index ties ==
// jax.lax.top_k order) is bit-identical to R1-R8.
__global__ __launch_bounds__(WPB * 64, 8)
void radius_graph_knn(const float* __restrict__ pos,
                      const int* __restrict__ batch,
                      float* __restrict__ out, int n) {
    __shared__ int jbuf[WPB][APW][CAP];   // per-wave scratch, no barriers
    __shared__ int win[WPB][APW][KNBR];

    const int tid  = threadIdx.x;
    const int lane = tid & 63;
    const int w    = tid >> 6;
    const int i0w  = (blockIdx.x * WPB + w) * APW;   // first atom of wave

    // ---- this wave's 2 atoms (broadcast loads, L2-resident)
    const int i0 = min(i0w, n - 1), i1 = min(i0w + 1, n - 1);
    const float x0 = pos[3 * i0], y0 = pos[3 * i0 + 1], z0 = pos[3 * i0 + 2];
    const float x1 = pos[3 * i1], y1 = pos[3 * i1 + 1], z1 = pos[3 * i1 + 2];
    const int b0 = batch[i0], b1 = batch[i1];

    // ---- candidate chunk-range detect (one gather round + one ballot).
    // Chunk cw intersects graphs [b0,b1] iff batch[64cw] <= b1 &&
    // batch[64cw+63] >= b0. batch sorted -> relevant chunks are a contiguous
    // run containing c0 (+-32 chunks = +-2048 atoms covers any union).
    const int nchunks = (n + 63) >> 6;
    const int c0 = i0w >> 6;
    const int cw = c0 - 32 + lane;
    bool rel = false;
    if (cw >= 0 && cw < nchunks) {
        const int s = batch[cw << 6];
        const int e = batch[min(n - 1, (cw << 6) + 63)];
        rel = (s <= b1) && (e >= b0);
    }
    const unsigned long long cm = __ballot(rel);
    const int cLo = c0 - 32 + (int)__builtin_ctzll(cm);
    const int cHi = c0 - 32 + (63 - (int)__builtin_clzll(cm));
    const int base = cLo << 6;
    const int stagedN = min(n, (cHi + 1) << 6) - base;   // multiple of 64

    // ---- fused dual-atom fp32 band scan, software-pipelined: iteration
    // t+1's loads issue before iteration t's ballot chains (latency overlap).
    int cnt0 = 0, cnt1 = 0;
    float xj, yj, zj; int bj;
    {
        const int tc = min(lane, stagedN - 1);
        const int j = base + tc;
        xj = pos[3 * j]; yj = pos[3 * j + 1]; zj = pos[3 * j + 2];
        bj = batch[j];
    }
    for (int t0 = 0; t0 < stagedN; t0 += 64) {
        // prefetch next iteration
        float xn = 0.f, yn = 0.f, zn = 0.f; int bn = 0;
        const int t0n = t0 + 64;
        if (t0n < stagedN) {
            const int tcn = min(t0n + lane, stagedN - 1);
            const int jn = base + tcn;
            xn = pos[3 * jn]; yn = pos[3 * jn + 1]; zn = pos[3 * jn + 2];
            bn = batch[jn];
        }
        // process current
        const int t = t0 + lane;
        const int j = base + min(t, stagedN - 1);
        {
            const float dx = x0 - xj, dy = y0 - yj, dz = z0 - zj;
            const float d2 = dx * dx + dy * dy + dz * dz;
            const bool valid = (t < stagedN) & (j != i0) & (bj == b0) &
                               (d2 <= 25.0f + BAND);
            const unsigned long long m = __ballot(valid);
            const int p = cnt0 + __popcll(m & ((1ULL << lane) - 1ULL));
            if (valid && p < CAP) jbuf[w][0][p] = j;
            cnt0 += __popcll(m);
        }
        {
            const float dx = x1 - xj, dy = y1 - yj, dz = z1 - zj;
            const float d2 = dx * dx + dy * dy + dz * dz;
            const bool valid = (t < stagedN) & (j != i1) & (bj == b1) &
                               (d2 <= 25.0f + BAND);
            const unsigned long long m = __ballot(valid);
            const int p = cnt1 + __popcll(m & ((1ULL << lane) - 1ULL));
            if (valid && p < CAP) jbuf[w][1][p] = j;
            cnt1 += __popcll(m);
        }
        xj = xn; yj = yn; zj = zn; bj = bn;
    }

    // ---- fused half-wave refine + rank: lanes 0-31 -> atom 0, 32-63 ->
    // atom 1. One fp64 gather round, one ballot, one width-32 rank loop.
    const int count0 = min(cnt0, CAP);
    const int count1 = min(cnt1, CAP);
    const int a = lane >> 5;          // which atom this lane serves
    const int q = lane & 31;          // candidate / neighbor slot
    const float xi = a ? x1 : x0, yi = a ? y1 : y0, zi = a ? z1 : z0;
    const int   ii = a ? i1 : i0;
    int ns_my = 0;

    if (count0 <= 32 && count1 <= 32) {
        const int cmy = a ? count1 : count0;
        double d2e = 1e300;
        int jmine = 0x7fffffff;
        bool valid = false;
        if (q < cmy) {
            const int j = jbuf[w][a][q];
            const double dx = (double)xi - (double)pos[3 * j];
            const double dy = (double)yi - (double)pos[3 * j + 1];
            const double dz = (double)zi - (double)pos[3 * j + 2];
            d2e = dx * dx + dy * dy + dz * dz;
            jmine = j;
            valid = (d2e <= STOP2);           // exact cutoff, as R1-R8
        }
        const unsigned long long vm = __ballot(valid);
        const unsigned int vmh = (unsigned int)(vm >> (a ? 32 : 0));
        ns_my = __popc(vmh);                  // <= 32 == KNBR
        const int cmax = max(count0, count1);
        int rank = 0;
        for (int s = 0; s < cmax; ++s) {
            const double ds = __shfl(d2e, s, 32);   // within own half
            const int    js = __shfl(jmine, s, 32);
            const bool   vs = (vmh >> s) & 1u;
            rank += (vs && (ds < d2e || (ds == d2e && js < jmine))) ? 1 : 0;
        }
        if (valid && rank < KNBR) win[w][a][rank] = jmine;
    } else {
        // serial fallback (bit-identical to R8) -- statistically never taken
        int nsel0 = 0, nsel1 = 0;
        for (int aa = 0; aa < APW; ++aa) {
            const int count = aa ? count1 : count0;
            const float xA = aa ? x1 : x0, yA = aa ? y1 : y0, zA = aa ? z1 : z0;
            const int   iA = aa ? i1 : i0;
            double d2e = 1e300;
            int jmine = 0x7fffffff;
            bool valid = false;
            if (lane < count) {
                const int j = jbuf[w][aa][lane];
                const double dx = (double)xA - (double)pos[3 * j];
                const double dy = (double)yA - (double)pos[3 * j + 1];
                const double dz = (double)zA - (double)pos[3 * j + 2];
                d2e = dx * dx + dy * dy + dz * dz;
                jmine = j;
                valid = (d2e <= STOP2);
            }
            (void)iA;
            const unsigned long long vm = __ballot(valid);
            int ns = __popcll(vm);
            if (ns > KNBR) ns = KNBR;
            if (aa) nsel1 = ns; else nsel0 = ns;
            int rank = 0;
            for (int s = 0; s < count; ++s) {
                const double ds = __shfl(d2e, s);
                const int    js = __shfl(jmine, s);
                const bool   vs = (vm >> s) & 1ULL;
                rank += (vs && (ds < d2e || (ds == d2e && js < jmine))) ? 1 : 0;
            }
            if (valid && rank < KNBR) win[w][aa][rank] = jmine;
        }
        ns_my = a ? nsel1 : nsel0;
    }

    // ---- fused full-wave epilogue: lanes 0-31 -> atom 0, 32-63 -> atom 1.
    // Atom rows are adjacent -> each store instruction covers 2x128B
    // contiguous.
    const long long NK = (long long)n * KNBR;
    float* row0 = out;
    float* row1 = out + NK;
    float* wgt  = out + 2 * NK;
    float* vec  = out + 3 * NK;
    float* msk  = out + 6 * NK;

    const bool v = q < ns_my;
    const int j = v ? win[w][a][q] : ii;          // pad with self (vec = 0)
    const float vx = xi - pos[3 * j];
    const float vy = yi - pos[3 * j + 1];
    const float vz = zi - pos[3 * j + 2];
    const float ww = v ? sqrtf(vx * vx + vy * vy + vz * vz) : 0.0f;
    const long long o = (long long)ii * KNBR + q;
    row0[o] = (float)ii;
    row1[o] = (float)j;
    wgt[o]  = ww;
    vec[3 * o + 0] = v ? vx : 0.0f;
    vec[3 * o + 1] = v ? vy : 0.0f;
    vec[3 * o + 2] = v ? vz : 0.0f;
    msk[o]  = v ? 1.0f : 0.0f;
}

extern "C" void kernel_launch(void* const* d_in, const int* in_sizes, int n_in,
                              void* d_out, int out_size, void* d_ws, size_t ws_size,
                              hipStream_t stream) {
    const float* pos   = (const float*)d_in[0];
    const int*   batch = (const int*)d_in[1];
    float* out = (float*)d_out;
    int n = in_sizes[1];  // 16384 atoms

    const int block = WPB * 64;
    const int grid = (n + APB - 1) / APB;  // 2048 blocks, 2 atoms per wave
    radius_graph_knn<<<grid, block, 0, stream>>>(pos, batch, out, n);
}